// Round 1
// baseline (86.137 us; speedup 1.0000x reference)
//
#include <hip/hip_runtime.h>

#define T_STEPS 151
#define NN 1024
#define DD 128
#define TILE 32
#define NTILE (NN / TILE)                     // 32
#define NBLOCKS (NTILE * (NTILE + 1) / 2)     // 528 upper-triangle tile pairs
#define LDSTRIDE 132                          // 132 floats: 16B-aligned rows
#define NPAIRS 523776.0f                      // 1024*1023/2

// ws layout (floats): [0..150] pos hist, [151..301] neg hist, [302] pos count

__global__ __launch_bounds__(256) void hist_kernel(
    const float* __restrict__ F, const int* __restrict__ cls, float* __restrict__ ws)
{
    __shared__ float As[TILE][LDSTRIDE];
    __shared__ float Bs[TILE][LDSTRIDE];
    __shared__ float hpos[T_STEPS];
    __shared__ float hneg[T_STEPS];
    __shared__ int   clsA[TILE];
    __shared__ int   clsB[TILE];
    __shared__ float pcount;

    const int t = threadIdx.x;

    // map linear block id -> (bi, bj) with bi <= bj
    int rem = blockIdx.x;
    int bi = 0;
    while (rem >= (NTILE - bi)) { rem -= (NTILE - bi); ++bi; }
    const int bj = bi + rem;

    for (int k = t; k < T_STEPS; k += 256) { hpos[k] = 0.f; hneg[k] = 0.f; }
    if (t == 0) pcount = 0.f;
    if (t < TILE)            clsA[t]        = cls[bi * TILE + t];
    else if (t < 2 * TILE)   clsB[t - TILE] = cls[bj * TILE + (t - TILE)];

    const float* Abase = F + (size_t)bi * TILE * DD;
    const float* Bbase = F + (size_t)bj * TILE * DD;
    // 32 rows x 128 cols = 1024 float4 per tile; 4 per thread, coalesced
    for (int idx = t; idx < TILE * DD / 4; idx += 256) {
        int r = idx >> 5;            // float4-chunks per row = 32
        int c = (idx & 31) << 2;
        *(float4*)&As[r][c] = *(const float4*)(Abase + r * DD + c);
        *(float4*)&Bs[r][c] = *(const float4*)(Bbase + r * DD + c);
    }
    __syncthreads();

    const int r  = t >> 5;           // 0..7
    const int c  = t & 31;           // 0..31
    const int gj = bj * TILE + c;
    const int cb = clsB[c];

    float acc[4][4];
    #pragma unroll
    for (int p = 0; p < 4; ++p)
        #pragma unroll
        for (int q = 0; q < 4; ++q) acc[p][q] = 0.f;

    // 4 dot products per thread (rows r, r+8, r+16, r+24 vs col c), B read shared
    #pragma unroll 4
    for (int k = 0; k < DD; k += 4) {
        float4 b4 = *(const float4*)&Bs[c][k];
        #pragma unroll
        for (int p = 0; p < 4; ++p) {
            float4 a4 = *(const float4*)&As[r + 8 * p][k];
            acc[p][0] += a4.x * b4.x;
            acc[p][1] += a4.y * b4.y;
            acc[p][2] += a4.z * b4.z;
            acc[p][3] += a4.w * b4.w;
        }
    }

    const float STEP = 2.0f / 150.0f;
    float myp = 0.f;
    {
        // Replicate the reference's fp32 mul/add/div sequences bit-exactly:
        // no FMA contraction here, or the delta==t equality tests can flip
        // for a whole bin and drop its weight.
        #pragma clang fp contract(off)
        #pragma unroll
        for (int p = 0; p < 4; ++p) {
            int i  = r + 8 * p;
            int gi = bi * TILE + i;
            if (gi < gj) {
                float s = (acc[p][0] + acc[p][1]) + (acc[p][2] + acc[p][3]);
                bool eqf = (clsA[i] == cb);
                float kf    = floorf((s + 1.0f) / STEP);
                float delta = kf * STEP - 1.0f;
                int   kk    = (int)kf;
                if (kk >= 0 && kk < T_STEPS) {
                    float tk = -1.0f + (float)kk * STEP;
                    if (delta == tk) {                       // reference indsb
                        float wb = (-s + tk + STEP) / STEP;
                        atomicAdd(eqf ? &hpos[kk] : &hneg[kk], wb);
                    }
                }
                int k1 = kk + 1;
                if (k1 >= 0 && k1 < T_STEPS) {
                    float tk1 = -1.0f + (float)k1 * STEP;
                    if (delta == (tk1 - STEP)) {             // reference indsa
                        float wa = (s - tk1 + STEP) / STEP;
                        atomicAdd(eqf ? &hpos[k1] : &hneg[k1], wa);
                    }
                }
                if (eqf) myp += 1.f;
            }
        }
    }
    atomicAdd(&pcount, myp);
    __syncthreads();

    for (int k = t; k < T_STEPS; k += 256) {
        float hp = hpos[k], hn = hneg[k];
        if (hp != 0.f) atomicAdd(&ws[k], hp);
        if (hn != 0.f) atomicAdd(&ws[T_STEPS + k], hn);
    }
    if (t == 0) atomicAdd(&ws[2 * T_STEPS], pcount);
}

__global__ __launch_bounds__(192) void final_kernel(
    const float* __restrict__ ws, float* __restrict__ out)
{
    __shared__ float hp[T_STEPS], hn[T_STEPS];
    int t = threadIdx.x;
    float pos = ws[2 * T_STEPS];
    float neg = NPAIRS - pos;
    if (t < T_STEPS) {
        hp[t] = ws[t] / pos;
        hn[t] = ws[T_STEPS + t] / neg;
    }
    __syncthreads();
    if (t == 0) {
        #pragma clang fp contract(off)
        float cdf = 0.f, loss = 0.f;
        for (int j = 0; j < T_STEPS; ++j) { cdf += hp[j]; loss += hn[j] * cdf; }
        *out = loss;
    }
}

extern "C" void kernel_launch(void* const* d_in, const int* in_sizes, int n_in,
                              void* d_out, int out_size, void* d_ws, size_t ws_size,
                              hipStream_t stream)
{
    const float* F   = (const float*)d_in[0];
    const int*   cls = (const int*)d_in[1];
    float*       ws  = (float*)d_ws;
    float*       out = (float*)d_out;

    hipMemsetAsync(d_ws, 0, (2 * T_STEPS + 1) * sizeof(float), stream);
    hist_kernel<<<NBLOCKS, 256, 0, stream>>>(F, cls, ws);
    final_kernel<<<1, 192, 0, stream>>>(ws, out);
}